// Round 15
// baseline (284.242 us; speedup 1.0000x reference)
//
#include <hip/hip_runtime.h>
#include <hip/hip_fp16.h>

#define N_NODES 100000
#define N_EDGES 3200000
#define N_GRAPHS 1000
#define NB 1024            // dst-range buckets
#define NPB 98             // nodes per bucket
#define CAP 3584           // per-bucket edge capacity (mean 3136 + 8 sigma)
#define EPB 8192           // edges per bucketing block

// ---------------- workspace layout (element offsets, 4B units) --------------
// dinv : float[N]        @ 0
// xp   : float[4N]       @ N
// t2A  : half [16N]      @ 5N    (8N units)  features 0..15 of (h1@W2)*dinv
// t2B  : half [16N]      @ 13N   (8N units)  features 16..31
// t3ph : half [16N]      @ 21N   (8N units)
// agg1 : float[4N]       @ 29N
// aggA : float[16N]      @ 33N
// aggB : float[16N]      @ 49N
// sval : float[N]        @ 65N   per-node head scalar
// row  : int  [N]        @ 81N   CSR start (global index into pay)
// dgar : int  [N]        @ 82N   in-degree (real edges)
// bcnt : int  [NB]       @ 83N
// pay  : uint [NB*CAP]   @ 83N+NB   packed (src | local_dst<<17), dst-sorted
// total ≈ 12.0M units ≈ 48 MB

__global__ void k_zero(int* __restrict__ bcnt) {
    int i = blockIdx.x * blockDim.x + threadIdx.x;
    if (i < NB) bcnt[i] = 0;
}

// two-level bucketize by dst: LDS histogram -> scan -> LDS place -> run flush
__global__ __launch_bounds__(256) void k_bucket(
    const int* __restrict__ src, const int* __restrict__ dst,
    int* __restrict__ bcnt, unsigned* __restrict__ pay) {
    __shared__ int cnt[NB];
    __shared__ int off[NB];
    __shared__ int scanbuf[256];
    __shared__ unsigned rec[EPB];

    int tid = threadIdx.x;
    int e0 = blockIdx.x * EPB;
    for (int i = tid; i < NB; i += 256) cnt[i] = 0;
    __syncthreads();

#pragma unroll
    for (int k = 0; k < EPB / 256; ++k) {
        int e = e0 + k * 256 + tid;
        if (e < N_EDGES) atomicAdd(&cnt[(unsigned)dst[e] / NPB], 1);
    }
    __syncthreads();

    int base = tid * 4;
    int c0 = cnt[base], c1 = cnt[base + 1], c2 = cnt[base + 2], c3 = cnt[base + 3];
    int part = c0 + c1 + c2 + c3;
    scanbuf[tid] = part;
    __syncthreads();
    for (int o = 1; o < 256; o <<= 1) {
        int v = (tid >= o) ? scanbuf[tid - o] : 0;
        __syncthreads();
        scanbuf[tid] += v;
        __syncthreads();
    }
    int ex = scanbuf[tid] - part;
    off[base]     = ex;
    off[base + 1] = ex + c0;
    off[base + 2] = ex + c0 + c1;
    off[base + 3] = ex + c0 + c1 + c2;
    __syncthreads();

#pragma unroll
    for (int k = 0; k < EPB / 256; ++k) {
        int e = e0 + k * 256 + tid;
        if (e < N_EDGES) {
            unsigned s = (unsigned)src[e];
            unsigned d = (unsigned)dst[e];
            unsigned b = d / NPB;
            unsigned ld = d - b * NPB;
            int p = atomicAdd(&off[b], 1);
            rec[p] = s | (ld << 17);
        }
    }
    __syncthreads();

    for (int b = tid; b < NB; b += 256) {
        int c = cnt[b];
        if (c == 0) continue;
        int ls = off[b] - c;
        int gb = atomicAdd(&bcnt[b], c);
        unsigned* dstp = pay + (size_t)b * CAP;
        for (int k = 0; k < c; ++k) {
            int gp = gb + k;
            if (gp < CAP) dstp[gp] = rec[ls + k];
        }
    }
}

// per-bucket: counting-sort records by LOCAL DST -> CSR; write row/deg;
// fused k_prep (dinv + pre-scaled xp) from the dst histogram.
__global__ __launch_bounds__(256) void k_sort(
    unsigned* __restrict__ pay, const int* __restrict__ bcnt,
    const float* __restrict__ x, float* __restrict__ dinv,
    float* __restrict__ xp, int* __restrict__ row, int* __restrict__ dgar) {
    __shared__ unsigned rec[CAP], rec2[CAP];
    __shared__ int hl[NPB], st[NPB], ofl[NPB];
    int tid = threadIdx.x;
    int b = blockIdx.x;
    int cnt = bcnt[b]; if (cnt > CAP) cnt = CAP;
    unsigned* P = pay + (size_t)b * CAP;

    if (tid < NPB) hl[tid] = 0;
    __syncthreads();

    for (int i = tid; i < cnt; i += 256) {
        unsigned w = P[i];
        rec[i] = w;
        atomicAdd(&hl[w >> 17], 1);
    }
    __syncthreads();

    if (tid == 0) {
        int run = 0;
        for (int l = 0; l < NPB; ++l) { st[l] = run; run += hl[l]; }
    }
    __syncthreads();
    if (tid < NPB) ofl[tid] = st[tid];

    // CSR metadata + fused prep for this bucket's own nodes
    if (tid < NPB) {
        int n = b * NPB + tid;
        if (n < N_NODES) {
            row[n]  = b * CAP + st[tid];
            dgar[n] = hl[tid];
            float di = rsqrtf((float)(hl[tid] + 1));   // +1 self-loop
            dinv[n] = di;
            float4 v = reinterpret_cast<const float4*>(x)[n];
            v.x *= di; v.y *= di; v.z *= di; v.w *= di;
            reinterpret_cast<float4*>(xp)[n] = v;
        }
    }
    __syncthreads();

    for (int i = tid; i < cnt; i += 256) {
        unsigned w = rec[i];
        int p = atomicAdd(&ofl[w >> 17], 1);
        rec2[p] = w;
    }
    __syncthreads();

    for (int i = tid; i < cnt; i += 256) P[i] = rec2[i];
}

// L1 gather: 4 lanes/node, scalar register accumulate, no LDS (xp = 1.6MB, L2-res)
__global__ __launch_bounds__(256) void k_g1(
    const float* __restrict__ xp, const unsigned* __restrict__ pay,
    const int* __restrict__ row, const int* __restrict__ dgar,
    float* __restrict__ agg1) {
    int tid = threadIdx.x;
    int lane = tid & 3;
    int n = blockIdx.x * 64 + (tid >> 2);
    if (n >= N_NODES) return;
    int r = row[n], d = dgar[n];
    const unsigned* P = pay + r;
    float acc = 0.0f;
#pragma unroll 4
    for (int j = 0; j < d; ++j) {
        int sn = P[j] & 0x1FFFF;
        acc += xp[sn * 4 + lane];
    }
    agg1[(size_t)n * 4 + lane] = acc;
}

// finish L1: a=(agg1+self)*dinv -> relu(@W1+b1) -> @W2 -> *dinv -> t2A|t2B (fp16)
__global__ __launch_bounds__(256) void k_dense1(
    const float* __restrict__ agg1, const float* __restrict__ xp,
    const float* __restrict__ dinv,
    const float* __restrict__ W1, const float* __restrict__ b1,
    const float* __restrict__ W2, __half* __restrict__ t2A,
    __half* __restrict__ t2B) {
    __shared__ float sW1[256], sb1[64], sW2[2048];
    int tid = threadIdx.x;
    sW1[tid] = W1[tid];
    if (tid < 64) sb1[tid] = b1[tid];
    for (int i = tid; i < 2048; i += 256) sW2[i] = W2[i];
    __syncthreads();

    int n = blockIdx.x * 256 + tid;
    if (n >= N_NODES) return;
    float di = dinv[n];
    float4 ag = reinterpret_cast<const float4*>(agg1)[n];
    float4 sv = reinterpret_cast<const float4*>(xp)[n];
    float a[4] = {(ag.x + sv.x) * di, (ag.y + sv.y) * di,
                  (ag.z + sv.z) * di, (ag.w + sv.w) * di};
    float t[32];
#pragma unroll
    for (int k = 0; k < 32; ++k) t[k] = 0.0f;
    for (int j = 0; j < 64; ++j) {
        float h = sb1[j];
#pragma unroll
        for (int i = 0; i < 4; ++i) h += a[i] * sW1[i * 64 + j];
        h = fmaxf(h, 0.0f);
#pragma unroll
        for (int k = 0; k < 32; ++k) t[k] += h * sW2[j * 32 + k];
    }
    __half2* oA = reinterpret_cast<__half2*>(t2A + (size_t)n * 16);
    __half2* oB = reinterpret_cast<__half2*>(t2B + (size_t)n * 16);
#pragma unroll
    for (int q = 0; q < 8; ++q) {
        oA[q] = __floats2half2_rn(t[2*q]      * di, t[2*q+1]      * di);
        oB[q] = __floats2half2_rn(t[16 + 2*q] * di, t[16 + 2*q+1] * di);
    }
}

// L2 gather half-pass: 4 lanes/node x 8B (4 fp16) per edge from a 3.2MB
// half-table (fits per-XCD L2). Launched twice, stream-serialized.
__global__ __launch_bounds__(256) void k_g2h(
    const __half* __restrict__ tbl, const unsigned* __restrict__ pay,
    const int* __restrict__ row, const int* __restrict__ dgar,
    float* __restrict__ aggOut) {
    int tid = threadIdx.x;
    int lane = tid & 3;
    int n = blockIdx.x * 64 + (tid >> 2);
    if (n >= N_NODES) return;
    int r = row[n], d = dgar[n];
    const unsigned* P = pay + r;
    float a0 = 0, a1 = 0, a2 = 0, a3 = 0;
#pragma unroll 4
    for (int j = 0; j < d; ++j) {
        int sn = P[j] & 0x1FFFF;
        union { uint2 u; __half2 h[2]; } U;
        U.u = *reinterpret_cast<const uint2*>(tbl + (size_t)sn * 16 + lane * 4);
        float2 f0 = __half22float2(U.h[0]);
        float2 f1 = __half22float2(U.h[1]);
        a0 += f0.x; a1 += f0.y; a2 += f1.x; a3 += f1.y;
    }
    *reinterpret_cast<float4*>(aggOut + (size_t)n * 16 + lane * 4) =
        make_float4(a0, a1, a2, a3);
}

// finish L2: h=relu((agg+self)*dinv+b2) -> @W3 -> *dinv -> t3ph (fp16)
__global__ __launch_bounds__(256) void k_dense2(
    const float* __restrict__ aggA, const float* __restrict__ aggB,
    const __half* __restrict__ t2A, const __half* __restrict__ t2B,
    const float* __restrict__ dinv,
    const float* __restrict__ b2, const float* __restrict__ W3,
    __half* __restrict__ t3ph) {
    __shared__ float sb2[32], sW3[512];
    int tid = threadIdx.x;
    if (tid < 32) sb2[tid] = b2[tid];
    for (int i = tid; i < 512; i += 256) sW3[i] = W3[i];
    __syncthreads();

    int n = blockIdx.x * 256 + tid;
    if (n >= N_NODES) return;
    float di = dinv[n];
    const float2* agA = reinterpret_cast<const float2*>(aggA + (size_t)n * 16);
    const float2* agB = reinterpret_cast<const float2*>(aggB + (size_t)n * 16);
    const __half2* spA = reinterpret_cast<const __half2*>(t2A + (size_t)n * 16);
    const __half2* spB = reinterpret_cast<const __half2*>(t2B + (size_t)n * 16);
    float h[32];
#pragma unroll
    for (int q = 0; q < 8; ++q) {
        float2 a = agA[q];
        float2 sv = __half22float2(spA[q]);
        h[2*q]   = fmaxf((a.x + sv.x) * di + sb2[2*q],   0.0f);
        h[2*q+1] = fmaxf((a.y + sv.y) * di + sb2[2*q+1], 0.0f);
    }
#pragma unroll
    for (int q = 0; q < 8; ++q) {
        float2 a = agB[q];
        float2 sv = __half22float2(spB[q]);
        h[16+2*q]   = fmaxf((a.x + sv.x) * di + sb2[16+2*q],   0.0f);
        h[16+2*q+1] = fmaxf((a.y + sv.y) * di + sb2[16+2*q+1], 0.0f);
    }
    float t[16];
#pragma unroll
    for (int k = 0; k < 16; ++k) t[k] = 0.0f;
    for (int j = 0; j < 32; ++j) {
#pragma unroll
        for (int k = 0; k < 16; ++k) t[k] += h[j] * sW3[j * 16 + k];
    }
    __half2* o = reinterpret_cast<__half2*>(t3ph + (size_t)n * 16);
#pragma unroll
    for (int q = 0; q < 8; ++q)
        o[q] = __floats2half2_rn(t[2*q] * di, t[2*q+1] * di);
}

// L3 gather + fused L3 finish + head dot: 4 lanes/node x 8B per edge.
__global__ __launch_bounds__(256) void k_g3(
    const __half* __restrict__ t3ph, const unsigned* __restrict__ pay,
    const int* __restrict__ row, const int* __restrict__ dgar,
    const float* __restrict__ dinv, const float* __restrict__ b3,
    const float* __restrict__ Wl, float* __restrict__ sval) {
    int tid = threadIdx.x;
    int lane = tid & 3;
    int n = blockIdx.x * 64 + (tid >> 2);
    if (n >= N_NODES) return;
    int r = row[n], d = dgar[n];
    const unsigned* P = pay + r;
    float a0 = 0, a1 = 0, a2 = 0, a3 = 0;
#pragma unroll 4
    for (int j = 0; j < d; ++j) {
        int sn = P[j] & 0x1FFFF;
        union { uint2 u; __half2 h[2]; } U;
        U.u = *reinterpret_cast<const uint2*>(t3ph + (size_t)sn * 16 + lane * 4);
        float2 f0 = __half22float2(U.h[0]);
        float2 f1 = __half22float2(U.h[1]);
        a0 += f0.x; a1 += f0.y; a2 += f1.x; a3 += f1.y;
    }
    union { uint2 u; __half2 h[2]; } S;
    S.u = *reinterpret_cast<const uint2*>(t3ph + (size_t)n * 16 + lane * 4);
    float2 s0 = __half22float2(S.h[0]);
    float2 s1 = __half22float2(S.h[1]);
    float di = dinv[n];
    float p = ((a0 + s0.x) * di + b3[lane * 4 + 0]) * Wl[lane * 4 + 0]
            + ((a1 + s0.y) * di + b3[lane * 4 + 1]) * Wl[lane * 4 + 1]
            + ((a2 + s1.x) * di + b3[lane * 4 + 2]) * Wl[lane * 4 + 2]
            + ((a3 + s1.y) * di + b3[lane * 4 + 3]) * Wl[lane * 4 + 3];
    p += __shfl_xor(p, 1);
    p += __shfl_xor(p, 2);
    if (lane == 0) sval[n] = p;
}

// mean-pool + head per graph: one wave per graph; binary-search the sorted
// batch array for [start,end), strided sum of sval, shfl reduce. No atomics.
__global__ __launch_bounds__(64) void k_poolg(
    const float* __restrict__ sval, const int* __restrict__ batch,
    const float* __restrict__ bl, float* __restrict__ out) {
    int g = blockIdx.x;
    int lo = 0, hi = N_NODES;
    while (lo < hi) { int m = (lo + hi) >> 1; if (batch[m] < g) lo = m + 1; else hi = m; }
    int s0 = lo;
    hi = N_NODES;
    while (lo < hi) { int m = (lo + hi) >> 1; if (batch[m] < g + 1) lo = m + 1; else hi = m; }
    int s1 = lo;
    float s = 0.0f;
    for (int i = s0 + threadIdx.x; i < s1; i += 64) s += sval[i];
#pragma unroll
    for (int o = 32; o > 0; o >>= 1) s += __shfl_down(s, o);
    if (threadIdx.x == 0) {
        float c = fmaxf((float)(s1 - s0), 1.0f);
        out[g] = fmaxf(s / c + bl[0], 0.0f);
    }
}

extern "C" void kernel_launch(void* const* d_in, const int* in_sizes, int n_in,
                              void* d_out, int out_size, void* d_ws, size_t ws_size,
                              hipStream_t stream) {
    const float* x  = (const float*)d_in[0];
    const float* W1 = (const float*)d_in[1];
    const float* b1 = (const float*)d_in[2];
    const float* W2 = (const float*)d_in[3];
    const float* b2 = (const float*)d_in[4];
    const float* W3 = (const float*)d_in[5];
    const float* b3 = (const float*)d_in[6];
    const float* Wl = (const float*)d_in[7];
    const float* bl = (const float*)d_in[8];
    const int*   ei = (const int*)d_in[9];        // [2, E] row-major
    const int* batch = (const int*)d_in[10];
    const int* src = ei;
    const int* dst = ei + N_EDGES;
    float* out = (float*)d_out;

    const size_t N = N_NODES;
    char* ws = (char*)d_ws;
    float*    dinv = (float*)   (ws);
    float*    xp   = (float*)   (ws + 4 * (N));
    __half*   t2A  = (__half*)  (ws + 4 * (5 * N));
    __half*   t2B  = (__half*)  (ws + 4 * (13 * N));
    __half*   t3ph = (__half*)  (ws + 4 * (21 * N));
    float*    agg1 = (float*)   (ws + 4 * (29 * N));
    float*    aggA = (float*)   (ws + 4 * (33 * N));
    float*    aggB = (float*)   (ws + 4 * (49 * N));
    float*    sval = (float*)   (ws + 4 * (65 * N));
    int*      row  = (int*)     (ws + 4 * (81 * N));
    int*      dgar = (int*)     (ws + 4 * (82 * N));
    int*      bcnt = (int*)     (ws + 4 * (83 * N));
    unsigned* pay  = (unsigned*)(ws + 4 * (83 * N + NB));

    const int B = 256;
    const int gN = (N_NODES + B - 1) / B;            // 391
    const int gB = (N_EDGES + EPB - 1) / EPB;        // 391
    const int gG = (N_NODES + 63) / 64;              // 1563

    k_zero  <<<(NB + B - 1) / B, B, 0, stream>>>(bcnt);
    k_bucket<<<gB, B, 0, stream>>>(src, dst, bcnt, pay);
    k_sort  <<<NB, B, 0, stream>>>(pay, bcnt, x, dinv, xp, row, dgar);
    k_g1    <<<gG, B, 0, stream>>>(xp, pay, row, dgar, agg1);
    k_dense1<<<gN, B, 0, stream>>>(agg1, xp, dinv, W1, b1, W2, t2A, t2B);
    k_g2h   <<<gG, B, 0, stream>>>(t2A, pay, row, dgar, aggA);
    k_g2h   <<<gG, B, 0, stream>>>(t2B, pay, row, dgar, aggB);
    k_dense2<<<gN, B, 0, stream>>>(aggA, aggB, t2A, t2B, dinv, b2, W3, t3ph);
    k_g3    <<<gG, B, 0, stream>>>(t3ph, pay, row, dgar, dinv, b3, Wl, sval);
    k_poolg <<<N_GRAPHS, 64, 0, stream>>>(sval, batch, bl, out);
}

// Round 16
// 282.511 us; speedup vs baseline: 1.0061x; 1.0061x over previous
//
#include <hip/hip_runtime.h>
#include <hip/hip_fp16.h>

#define N_NODES 100000
#define N_EDGES 3200000
#define N_GRAPHS 1000
#define NB 1024            // dst-range buckets
#define NPB 98             // nodes per bucket
#define CAP 3584           // per-bucket edge capacity (mean 3136 + 8 sigma)
#define EPB 4096           // edges per bucketing block
#define EPT 16             // edges per thread (EPB/256)

// ---------------- workspace layout (element offsets, 4B units) --------------
// dinv : float[N]        @ 0
// xp   : float[4N]       @ N
// t2ph : half [32N]      @ 5N    (16N units)
// t3ph : half [16N]      @ 21N   (8N units)
// agg1 : float[4N]       @ 29N
// agg2 : float[32N]      @ 33N
// sval : float[N]        @ 65N   per-node head scalar
// row  : int  [N]        @ 81N   CSR start (global index into pay)
// dgar : int  [N]        @ 82N   in-degree (real edges)
// bcnt : int  [NB]       @ 83N
// pay  : uint [NB*CAP]   @ 83N+NB   packed (src | local_dst<<17), dst-sorted
// total ≈ 12.0M units ≈ 48 MB

__global__ void k_zero(int* __restrict__ bcnt) {
    int i = blockIdx.x * blockDim.x + threadIdx.x;
    if (i < NB) bcnt[i] = 0;
}

// two-level bucketize by dst. Records decoded ONCE into registers (phase 1),
// placed from registers (phase 3) — no global re-read. 25.5KB LDS.
__global__ __launch_bounds__(256) void k_bucket(
    const int* __restrict__ src, const int* __restrict__ dst,
    int* __restrict__ bcnt, unsigned* __restrict__ pay) {
    __shared__ int cnt[NB];        // 4KB
    __shared__ int off[NB];        // 4KB
    __shared__ int scanbuf[256];   // 1KB
    __shared__ unsigned rec[EPB];  // 16KB

    int tid = threadIdx.x;
    int e0 = blockIdx.x * EPB;
    for (int i = tid; i < NB; i += 256) cnt[i] = 0;
    __syncthreads();

    unsigned wreg[EPT], breg[EPT];
#pragma unroll
    for (int k = 0; k < EPT; ++k) {
        int e = e0 + k * 256 + tid;
        if (e < N_EDGES) {
            unsigned s = (unsigned)src[e];
            unsigned d = (unsigned)dst[e];
            unsigned b = d / NPB;
            unsigned ld = d - b * NPB;
            wreg[k] = s | (ld << 17);
            breg[k] = b;
            atomicAdd(&cnt[b], 1);
        } else {
            breg[k] = 0xFFFFFFFFu;
        }
    }
    __syncthreads();

    // exclusive scan of cnt[1024] (thread owns 4 consecutive buckets)
    int base = tid * 4;
    int c0 = cnt[base], c1 = cnt[base + 1], c2 = cnt[base + 2], c3 = cnt[base + 3];
    int part = c0 + c1 + c2 + c3;
    scanbuf[tid] = part;
    __syncthreads();
    for (int o = 1; o < 256; o <<= 1) {
        int v = (tid >= o) ? scanbuf[tid - o] : 0;
        __syncthreads();
        scanbuf[tid] += v;
        __syncthreads();
    }
    int ex = scanbuf[tid] - part;
    off[base]     = ex;
    off[base + 1] = ex + c0;
    off[base + 2] = ex + c0 + c1;
    off[base + 3] = ex + c0 + c1 + c2;
    __syncthreads();

    // place from registers, grouped by bucket in LDS
#pragma unroll
    for (int k = 0; k < EPT; ++k) {
        if (breg[k] != 0xFFFFFFFFu) {
            int p = atomicAdd(&off[breg[k]], 1);
            rec[p] = wreg[k];
        }
    }
    __syncthreads();

    // flush contiguous runs (one global cursor atomic per run)
    for (int b = tid; b < NB; b += 256) {
        int c = cnt[b];
        if (c == 0) continue;
        int ls = off[b] - c;
        int gb = atomicAdd(&bcnt[b], c);
        unsigned* dstp = pay + (size_t)b * CAP;
        for (int k = 0; k < c; ++k) {
            int gp = gb + k;
            if (gp < CAP) dstp[gp] = rec[ls + k];
        }
    }
}

// per-bucket: counting-sort records by LOCAL DST -> CSR; write row/deg;
// fused k_prep (dinv + pre-scaled xp). Parallel 128-lane scan.
__global__ __launch_bounds__(256) void k_sort(
    unsigned* __restrict__ pay, const int* __restrict__ bcnt,
    const float* __restrict__ x, float* __restrict__ dinv,
    float* __restrict__ xp, int* __restrict__ row, int* __restrict__ dgar) {
    __shared__ unsigned rec[CAP], rec2[CAP];
    __shared__ int hl[NPB], st[NPB], ofl[NPB], sc[128];
    int tid = threadIdx.x;
    int b = blockIdx.x;
    int cnt = bcnt[b]; if (cnt > CAP) cnt = CAP;
    unsigned* P = pay + (size_t)b * CAP;

    if (tid < NPB) hl[tid] = 0;
    __syncthreads();

    for (int i = tid; i < cnt; i += 256) {
        unsigned w = P[i];
        rec[i] = w;
        atomicAdd(&hl[w >> 17], 1);
    }
    __syncthreads();

    // parallel exclusive scan of hl[98] (Hillis-Steele over 128 lanes)
    if (tid < 128) sc[tid] = (tid < NPB) ? hl[tid] : 0;
    __syncthreads();
    for (int o = 1; o < 128; o <<= 1) {
        int v = 0;
        if (tid < 128 && tid >= o) v = sc[tid - o];
        __syncthreads();
        if (tid < 128) sc[tid] += v;
        __syncthreads();
    }
    if (tid < NPB) {
        int s = sc[tid] - hl[tid];       // exclusive
        st[tid] = s;
        ofl[tid] = s;
    }
    __syncthreads();

    // CSR metadata + fused prep for this bucket's own nodes
    if (tid < NPB) {
        int n = b * NPB + tid;
        if (n < N_NODES) {
            row[n]  = b * CAP + st[tid];
            dgar[n] = hl[tid];
            float di = rsqrtf((float)(hl[tid] + 1));   // +1 self-loop
            dinv[n] = di;
            float4 v = reinterpret_cast<const float4*>(x)[n];
            v.x *= di; v.y *= di; v.z *= di; v.w *= di;
            reinterpret_cast<float4*>(xp)[n] = v;
        }
    }
    __syncthreads();

    for (int i = tid; i < cnt; i += 256) {
        unsigned w = rec[i];
        int p = atomicAdd(&ofl[w >> 17], 1);
        rec2[p] = w;
    }
    __syncthreads();

    for (int i = tid; i < cnt; i += 256) P[i] = rec2[i];
}

// L1 gather: 4 lanes/node, scalar register accumulate, no LDS
__global__ __launch_bounds__(256) void k_g1(
    const float* __restrict__ xp, const unsigned* __restrict__ pay,
    const int* __restrict__ row, const int* __restrict__ dgar,
    float* __restrict__ agg1) {
    int tid = threadIdx.x;
    int lane = tid & 3;
    int n = blockIdx.x * 64 + (tid >> 2);
    if (n >= N_NODES) return;
    int r = row[n], d = dgar[n];
    const unsigned* P = pay + r;
    float acc = 0.0f;
#pragma unroll 4
    for (int j = 0; j < d; ++j) {
        int sn = P[j] & 0x1FFFF;
        acc += xp[sn * 4 + lane];
    }
    agg1[(size_t)n * 4 + lane] = acc;
}

// finish L1: a=(agg1+self)*dinv -> relu(@W1+b1) -> @W2 -> *dinv -> t2ph (fp16)
__global__ __launch_bounds__(256) void k_dense1(
    const float* __restrict__ agg1, const float* __restrict__ xp,
    const float* __restrict__ dinv,
    const float* __restrict__ W1, const float* __restrict__ b1,
    const float* __restrict__ W2, __half* __restrict__ t2ph) {
    __shared__ float sW1[256], sb1[64], sW2[2048];
    int tid = threadIdx.x;
    sW1[tid] = W1[tid];
    if (tid < 64) sb1[tid] = b1[tid];
    for (int i = tid; i < 2048; i += 256) sW2[i] = W2[i];
    __syncthreads();

    int n = blockIdx.x * 256 + tid;
    if (n >= N_NODES) return;
    float di = dinv[n];
    float4 ag = reinterpret_cast<const float4*>(agg1)[n];
    float4 sv = reinterpret_cast<const float4*>(xp)[n];
    float a[4] = {(ag.x + sv.x) * di, (ag.y + sv.y) * di,
                  (ag.z + sv.z) * di, (ag.w + sv.w) * di};
    float t[32];
#pragma unroll
    for (int k = 0; k < 32; ++k) t[k] = 0.0f;
    for (int j = 0; j < 64; ++j) {
        float h = sb1[j];
#pragma unroll
        for (int i = 0; i < 4; ++i) h += a[i] * sW1[i * 64 + j];
        h = fmaxf(h, 0.0f);
#pragma unroll
        for (int k = 0; k < 32; ++k) t[k] += h * sW2[j * 32 + k];
    }
    __half2* o = reinterpret_cast<__half2*>(t2ph + (size_t)n * 32);
#pragma unroll
    for (int q = 0; q < 16; ++q)
        o[q] = __floats2half2_rn(t[2*q] * di, t[2*q+1] * di);
}

// L2 gather: 4 lanes/node x 16B (8 fp16) per edge, register accumulate
__global__ __launch_bounds__(256) void k_g2(
    const __half* __restrict__ t2ph, const unsigned* __restrict__ pay,
    const int* __restrict__ row, const int* __restrict__ dgar,
    float* __restrict__ agg2) {
    int tid = threadIdx.x;
    int lane = tid & 3;
    int n = blockIdx.x * 64 + (tid >> 2);
    if (n >= N_NODES) return;
    int r = row[n], d = dgar[n];
    const unsigned* P = pay + r;
    float a0 = 0, a1 = 0, a2 = 0, a3 = 0, a4 = 0, a5 = 0, a6 = 0, a7 = 0;
#pragma unroll 4
    for (int j = 0; j < d; ++j) {
        int sn = P[j] & 0x1FFFF;
        union { uint4 u; __half2 h[4]; } U;
        U.u = *reinterpret_cast<const uint4*>(t2ph + (size_t)sn * 32 + lane * 8);
        float2 f0 = __half22float2(U.h[0]);
        float2 f1 = __half22float2(U.h[1]);
        float2 f2 = __half22float2(U.h[2]);
        float2 f3 = __half22float2(U.h[3]);
        a0 += f0.x; a1 += f0.y; a2 += f1.x; a3 += f1.y;
        a4 += f2.x; a5 += f2.y; a6 += f3.x; a7 += f3.y;
    }
    float4* o = reinterpret_cast<float4*>(agg2 + (size_t)n * 32 + lane * 8);
    o[0] = make_float4(a0, a1, a2, a3);
    o[1] = make_float4(a4, a5, a6, a7);
}

// finish L2: h=relu((agg2+self)*dinv+b2) -> @W3 -> *dinv -> t3ph (fp16)
__global__ __launch_bounds__(256) void k_dense2(
    const float* __restrict__ agg2, const __half* __restrict__ t2ph,
    const float* __restrict__ dinv,
    const float* __restrict__ b2, const float* __restrict__ W3,
    __half* __restrict__ t3ph) {
    __shared__ float sb2[32], sW3[512];
    int tid = threadIdx.x;
    if (tid < 32) sb2[tid] = b2[tid];
    for (int i = tid; i < 512; i += 256) sW3[i] = W3[i];
    __syncthreads();

    int n = blockIdx.x * 256 + tid;
    if (n >= N_NODES) return;
    float di = dinv[n];
    const float2* ag = reinterpret_cast<const float2*>(agg2 + (size_t)n * 32);
    const __half2* sp = reinterpret_cast<const __half2*>(t2ph + (size_t)n * 32);
    float h[32];
#pragma unroll
    for (int q = 0; q < 16; ++q) {
        float2 a = ag[q];
        float2 sv = __half22float2(sp[q]);
        h[2*q]   = fmaxf((a.x + sv.x) * di + sb2[2*q],   0.0f);
        h[2*q+1] = fmaxf((a.y + sv.y) * di + sb2[2*q+1], 0.0f);
    }
    float t[16];
#pragma unroll
    for (int k = 0; k < 16; ++k) t[k] = 0.0f;
    for (int j = 0; j < 32; ++j) {
#pragma unroll
        for (int k = 0; k < 16; ++k) t[k] += h[j] * sW3[j * 16 + k];
    }
    __half2* o = reinterpret_cast<__half2*>(t3ph + (size_t)n * 16);
#pragma unroll
    for (int q = 0; q < 8; ++q)
        o[q] = __floats2half2_rn(t[2*q] * di, t[2*q+1] * di);
}

// L3 gather + fused L3 finish + head dot: 4 lanes/node x 8B per edge.
__global__ __launch_bounds__(256) void k_g3(
    const __half* __restrict__ t3ph, const unsigned* __restrict__ pay,
    const int* __restrict__ row, const int* __restrict__ dgar,
    const float* __restrict__ dinv, const float* __restrict__ b3,
    const float* __restrict__ Wl, float* __restrict__ sval) {
    int tid = threadIdx.x;
    int lane = tid & 3;
    int n = blockIdx.x * 64 + (tid >> 2);
    if (n >= N_NODES) return;
    int r = row[n], d = dgar[n];
    const unsigned* P = pay + r;
    float a0 = 0, a1 = 0, a2 = 0, a3 = 0;
#pragma unroll 4
    for (int j = 0; j < d; ++j) {
        int sn = P[j] & 0x1FFFF;
        union { uint2 u; __half2 h[2]; } U;
        U.u = *reinterpret_cast<const uint2*>(t3ph + (size_t)sn * 16 + lane * 4);
        float2 f0 = __half22float2(U.h[0]);
        float2 f1 = __half22float2(U.h[1]);
        a0 += f0.x; a1 += f0.y; a2 += f1.x; a3 += f1.y;
    }
    union { uint2 u; __half2 h[2]; } S;
    S.u = *reinterpret_cast<const uint2*>(t3ph + (size_t)n * 16 + lane * 4);
    float2 s0 = __half22float2(S.h[0]);
    float2 s1 = __half22float2(S.h[1]);
    float di = dinv[n];
    float p = ((a0 + s0.x) * di + b3[lane * 4 + 0]) * Wl[lane * 4 + 0]
            + ((a1 + s0.y) * di + b3[lane * 4 + 1]) * Wl[lane * 4 + 1]
            + ((a2 + s1.x) * di + b3[lane * 4 + 2]) * Wl[lane * 4 + 2]
            + ((a3 + s1.y) * di + b3[lane * 4 + 3]) * Wl[lane * 4 + 3];
    p += __shfl_xor(p, 1);
    p += __shfl_xor(p, 2);
    if (lane == 0) sval[n] = p;
}

// mean-pool + head per graph: one wave per graph; binary-search the sorted
// batch array for [start,end), strided sum of sval, shfl reduce. No atomics.
__global__ __launch_bounds__(64) void k_poolg(
    const float* __restrict__ sval, const int* __restrict__ batch,
    const float* __restrict__ bl, float* __restrict__ out) {
    int g = blockIdx.x;
    int lo = 0, hi = N_NODES;
    while (lo < hi) { int m = (lo + hi) >> 1; if (batch[m] < g) lo = m + 1; else hi = m; }
    int s0 = lo;
    hi = N_NODES;
    while (lo < hi) { int m = (lo + hi) >> 1; if (batch[m] < g + 1) lo = m + 1; else hi = m; }
    int s1 = lo;
    float s = 0.0f;
    for (int i = s0 + threadIdx.x; i < s1; i += 64) s += sval[i];
#pragma unroll
    for (int o = 32; o > 0; o >>= 1) s += __shfl_down(s, o);
    if (threadIdx.x == 0) {
        float c = fmaxf((float)(s1 - s0), 1.0f);
        out[g] = fmaxf(s / c + bl[0], 0.0f);
    }
}

extern "C" void kernel_launch(void* const* d_in, const int* in_sizes, int n_in,
                              void* d_out, int out_size, void* d_ws, size_t ws_size,
                              hipStream_t stream) {
    const float* x  = (const float*)d_in[0];
    const float* W1 = (const float*)d_in[1];
    const float* b1 = (const float*)d_in[2];
    const float* W2 = (const float*)d_in[3];
    const float* b2 = (const float*)d_in[4];
    const float* W3 = (const float*)d_in[5];
    const float* b3 = (const float*)d_in[6];
    const float* Wl = (const float*)d_in[7];
    const float* bl = (const float*)d_in[8];
    const int*   ei = (const int*)d_in[9];        // [2, E] row-major
    const int* batch = (const int*)d_in[10];
    const int* src = ei;
    const int* dst = ei + N_EDGES;
    float* out = (float*)d_out;

    const size_t N = N_NODES;
    char* ws = (char*)d_ws;
    float*    dinv = (float*)   (ws);
    float*    xp   = (float*)   (ws + 4 * (N));
    __half*   t2ph = (__half*)  (ws + 4 * (5 * N));
    __half*   t3ph = (__half*)  (ws + 4 * (21 * N));
    float*    agg1 = (float*)   (ws + 4 * (29 * N));
    float*    agg2 = (float*)   (ws + 4 * (33 * N));
    float*    sval = (float*)   (ws + 4 * (65 * N));
    int*      row  = (int*)     (ws + 4 * (81 * N));
    int*      dgar = (int*)     (ws + 4 * (82 * N));
    int*      bcnt = (int*)     (ws + 4 * (83 * N));
    unsigned* pay  = (unsigned*)(ws + 4 * (83 * N + NB));

    const int B = 256;
    const int gN = (N_NODES + B - 1) / B;            // 391
    const int gB = (N_EDGES + EPB - 1) / EPB;        // 782
    const int gG = (N_NODES + 63) / 64;              // 1563

    k_zero  <<<(NB + B - 1) / B, B, 0, stream>>>(bcnt);
    k_bucket<<<gB, B, 0, stream>>>(src, dst, bcnt, pay);
    k_sort  <<<NB, B, 0, stream>>>(pay, bcnt, x, dinv, xp, row, dgar);
    k_g1    <<<gG, B, 0, stream>>>(xp, pay, row, dgar, agg1);
    k_dense1<<<gN, B, 0, stream>>>(agg1, xp, dinv, W1, b1, W2, t2ph);
    k_g2    <<<gG, B, 0, stream>>>(t2ph, pay, row, dgar, agg2);
    k_dense2<<<gN, B, 0, stream>>>(agg2, t2ph, dinv, b2, W3, t3ph);
    k_g3    <<<gG, B, 0, stream>>>(t3ph, pay, row, dgar, dinv, b3, Wl, sval);
    k_poolg <<<N_GRAPHS, 64, 0, stream>>>(sval, batch, bl, out);
}

// Round 17
// 252.898 us; speedup vs baseline: 1.1239x; 1.1171x over previous
//
#include <hip/hip_runtime.h>
#include <hip/hip_fp16.h>

#define N_NODES 100000
#define N_EDGES 3200000
#define N_GRAPHS 1000
#define NB 1024            // dst-range buckets
#define NPB 98             // nodes per bucket
#define CAP 3584           // per-bucket edge capacity (mean 3136 + 8 sigma)
#define EPB 8192           // edges per bucketing block
#define EPT 32             // edges per thread (EPB/256)
#define NCH 8              // src chunks (t2ph slice 0.8MB fits L2)
#define CHN 12500          // nodes per chunk
#define PBINS (NPB * NCH)  // 784 composite sort bins

// ---------------- workspace layout (element offsets, 4B units) --------------
// dinv : float[N]        @ 0
// xp   : float[4N]       @ N
// t2ph : half [32N]      @ 5N    (16N units)
// t3ph : half [16N]      @ 21N   (8N units)
// agg1 : float[4N]       @ 29N
// agg2 : float[32N]      @ 33N
// sval : float[N]        @ 65N
// row  : int  [N]        @ 81N
// dgar : int  [N]        @ 82N
// bcnt : int  [NB]       @ 83N
// pay  : uint [NB*CAP]   @ 83N+NB   packed (src | local_dst<<17), (ld,chunk)-sorted
// total ≈ 12.0M units ≈ 48 MB

__global__ void k_zero(int* __restrict__ bcnt) {
    int i = blockIdx.x * blockDim.x + threadIdx.x;
    if (i < NB) bcnt[i] = 0;
}

// two-level bucketize by dst; records decoded once into registers. 41KB LDS.
__global__ __launch_bounds__(256) void k_bucket(
    const int* __restrict__ src, const int* __restrict__ dst,
    int* __restrict__ bcnt, unsigned* __restrict__ pay) {
    __shared__ int cnt[NB];
    __shared__ int off[NB];
    __shared__ int scanbuf[256];
    __shared__ unsigned rec[EPB];   // 32KB

    int tid = threadIdx.x;
    int e0 = blockIdx.x * EPB;
    for (int i = tid; i < NB; i += 256) cnt[i] = 0;
    __syncthreads();

    unsigned wreg[EPT], breg[EPT];
#pragma unroll
    for (int k = 0; k < EPT; ++k) {
        int e = e0 + k * 256 + tid;
        if (e < N_EDGES) {
            unsigned s = (unsigned)src[e];
            unsigned d = (unsigned)dst[e];
            unsigned b = d / NPB;
            unsigned ld = d - b * NPB;
            wreg[k] = s | (ld << 17);
            breg[k] = b;
            atomicAdd(&cnt[b], 1);
        } else {
            breg[k] = 0xFFFFFFFFu;
        }
    }
    __syncthreads();

    int base = tid * 4;
    int c0 = cnt[base], c1 = cnt[base + 1], c2 = cnt[base + 2], c3 = cnt[base + 3];
    int part = c0 + c1 + c2 + c3;
    scanbuf[tid] = part;
    __syncthreads();
    for (int o = 1; o < 256; o <<= 1) {
        int v = (tid >= o) ? scanbuf[tid - o] : 0;
        __syncthreads();
        scanbuf[tid] += v;
        __syncthreads();
    }
    int ex = scanbuf[tid] - part;
    off[base]     = ex;
    off[base + 1] = ex + c0;
    off[base + 2] = ex + c0 + c1;
    off[base + 3] = ex + c0 + c1 + c2;
    __syncthreads();

#pragma unroll
    for (int k = 0; k < EPT; ++k) {
        if (breg[k] != 0xFFFFFFFFu) {
            int p = atomicAdd(&off[breg[k]], 1);
            rec[p] = wreg[k];
        }
    }
    __syncthreads();

    for (int b = tid; b < NB; b += 256) {
        int c = cnt[b];
        if (c == 0) continue;
        int ls = off[b] - c;
        int gb = atomicAdd(&bcnt[b], c);
        unsigned* dstp = pay + (size_t)b * CAP;
        for (int k = 0; k < c; ++k) {
            int gp = gb + k;
            if (gp < CAP) dstp[gp] = rec[ls + k];
        }
    }
}

// per-bucket: counting-sort by composite key (local_dst*8 + src_chunk) -> CSR
// whose per-node segments are src-chunk-ordered (L2-phased gathers).
// Also emits row/dgar and fused prep (dinv + pre-scaled xp).
__global__ __launch_bounds__(256) void k_sort(
    unsigned* __restrict__ pay, const int* __restrict__ bcnt,
    const float* __restrict__ x, float* __restrict__ dinv,
    float* __restrict__ xp, int* __restrict__ row, int* __restrict__ dgar) {
    __shared__ unsigned rec[CAP], rec2[CAP];            // 28.7KB
    __shared__ int cnb[PBINS], exl[PBINS], ofl[PBINS];  // 9.4KB
    __shared__ int scanbuf[256];
    int tid = threadIdx.x;
    int b = blockIdx.x;
    int cnt = bcnt[b]; if (cnt > CAP) cnt = CAP;
    unsigned* P = pay + (size_t)b * CAP;

    for (int i = tid; i < PBINS; i += 256) cnb[i] = 0;
    __syncthreads();

    for (int i = tid; i < cnt; i += 256) {
        unsigned w = P[i];
        rec[i] = w;
        int key = (int)(w >> 17) * NCH + (int)((w & 0x1FFFF) / CHN);
        atomicAdd(&cnb[key], 1);
    }
    __syncthreads();

    // exclusive scan of cnb[784]: thread t<196 owns bins 4t..4t+3
    int part = 0, c0 = 0, c1 = 0, c2 = 0, c3 = 0;
    int base = tid * 4;
    if (base < PBINS) {
        c0 = cnb[base]; c1 = cnb[base + 1]; c2 = cnb[base + 2]; c3 = cnb[base + 3];
        part = c0 + c1 + c2 + c3;
    }
    scanbuf[tid] = part;
    __syncthreads();
    for (int o = 1; o < 256; o <<= 1) {
        int v = (tid >= o) ? scanbuf[tid - o] : 0;
        __syncthreads();
        scanbuf[tid] += v;
        __syncthreads();
    }
    if (base < PBINS) {
        int ex = scanbuf[tid] - part;
        exl[base]     = ex;
        exl[base + 1] = ex + c0;
        exl[base + 2] = ex + c0 + c1;
        exl[base + 3] = ex + c0 + c1 + c2;
        ofl[base]     = exl[base];
        ofl[base + 1] = exl[base + 1];
        ofl[base + 2] = exl[base + 2];
        ofl[base + 3] = exl[base + 3];
    }
    __syncthreads();

    // CSR metadata + fused prep for this bucket's own nodes
    if (tid < NPB) {
        int n = b * NPB + tid;
        if (n < N_NODES) {
            int s0 = exl[tid * NCH];
            int s1 = exl[tid * NCH + NCH - 1] + cnb[tid * NCH + NCH - 1];
            row[n]  = b * CAP + s0;
            int dg  = s1 - s0;
            dgar[n] = dg;
            float di = rsqrtf((float)(dg + 1));   // +1 self-loop
            dinv[n] = di;
            float4 v = reinterpret_cast<const float4*>(x)[n];
            v.x *= di; v.y *= di; v.z *= di; v.w *= di;
            reinterpret_cast<float4*>(xp)[n] = v;
        }
    }
    __syncthreads();

    for (int i = tid; i < cnt; i += 256) {
        unsigned w = rec[i];
        int key = (int)(w >> 17) * NCH + (int)((w & 0x1FFFF) / CHN);
        int p = atomicAdd(&ofl[key], 1);
        rec2[p] = w;
    }
    __syncthreads();

    for (int i = tid; i < cnt; i += 256) P[i] = rec2[i];
}

// L1 gather: 4 lanes/node, register accumulate (xp = 1.6MB, L2-resident)
__global__ __launch_bounds__(256) void k_g1(
    const float* __restrict__ xp, const unsigned* __restrict__ pay,
    const int* __restrict__ row, const int* __restrict__ dgar,
    float* __restrict__ agg1) {
    int tid = threadIdx.x;
    int lane = tid & 3;
    int n = blockIdx.x * 64 + (tid >> 2);
    if (n >= N_NODES) return;
    int r = row[n], d = dgar[n];
    const unsigned* P = pay + r;
    float acc = 0.0f;
#pragma unroll 4
    for (int j = 0; j < d; ++j) {
        int sn = P[j] & 0x1FFFF;
        acc += xp[sn * 4 + lane];
    }
    agg1[(size_t)n * 4 + lane] = acc;
}

// finish L1: a=(agg1+self)*dinv -> relu(@W1+b1) -> @W2 -> *dinv -> t2ph (fp16)
__global__ __launch_bounds__(256) void k_dense1(
    const float* __restrict__ agg1, const float* __restrict__ xp,
    const float* __restrict__ dinv,
    const float* __restrict__ W1, const float* __restrict__ b1,
    const float* __restrict__ W2, __half* __restrict__ t2ph) {
    __shared__ float sW1[256], sb1[64], sW2[2048];
    int tid = threadIdx.x;
    sW1[tid] = W1[tid];
    if (tid < 64) sb1[tid] = b1[tid];
    for (int i = tid; i < 2048; i += 256) sW2[i] = W2[i];
    __syncthreads();

    int n = blockIdx.x * 256 + tid;
    if (n >= N_NODES) return;
    float di = dinv[n];
    float4 ag = reinterpret_cast<const float4*>(agg1)[n];
    float4 sv = reinterpret_cast<const float4*>(xp)[n];
    float a[4] = {(ag.x + sv.x) * di, (ag.y + sv.y) * di,
                  (ag.z + sv.z) * di, (ag.w + sv.w) * di};
    float t[32];
#pragma unroll
    for (int k = 0; k < 32; ++k) t[k] = 0.0f;
    for (int j = 0; j < 64; ++j) {
        float h = sb1[j];
#pragma unroll
        for (int i = 0; i < 4; ++i) h += a[i] * sW1[i * 64 + j];
        h = fmaxf(h, 0.0f);
#pragma unroll
        for (int k = 0; k < 32; ++k) t[k] += h * sW2[j * 32 + k];
    }
    __half2* o = reinterpret_cast<__half2*>(t2ph + (size_t)n * 32);
#pragma unroll
    for (int q = 0; q < 16; ++q)
        o[q] = __floats2half2_rn(t[2*q] * di, t[2*q+1] * di);
}

// L2 gather: 4 lanes/node x 16B per edge; edge lists are src-chunk-ordered
__global__ __launch_bounds__(256) void k_g2(
    const __half* __restrict__ t2ph, const unsigned* __restrict__ pay,
    const int* __restrict__ row, const int* __restrict__ dgar,
    float* __restrict__ agg2) {
    int tid = threadIdx.x;
    int lane = tid & 3;
    int n = blockIdx.x * 64 + (tid >> 2);
    if (n >= N_NODES) return;
    int r = row[n], d = dgar[n];
    const unsigned* P = pay + r;
    float a0 = 0, a1 = 0, a2 = 0, a3 = 0, a4 = 0, a5 = 0, a6 = 0, a7 = 0;
#pragma unroll 4
    for (int j = 0; j < d; ++j) {
        int sn = P[j] & 0x1FFFF;
        union { uint4 u; __half2 h[4]; } U;
        U.u = *reinterpret_cast<const uint4*>(t2ph + (size_t)sn * 32 + lane * 8);
        float2 f0 = __half22float2(U.h[0]);
        float2 f1 = __half22float2(U.h[1]);
        float2 f2 = __half22float2(U.h[2]);
        float2 f3 = __half22float2(U.h[3]);
        a0 += f0.x; a1 += f0.y; a2 += f1.x; a3 += f1.y;
        a4 += f2.x; a5 += f2.y; a6 += f3.x; a7 += f3.y;
    }
    float4* o = reinterpret_cast<float4*>(agg2 + (size_t)n * 32 + lane * 8);
    o[0] = make_float4(a0, a1, a2, a3);
    o[1] = make_float4(a4, a5, a6, a7);
}

// finish L2: h=relu((agg2+self)*dinv+b2) -> @W3 -> *dinv -> t3ph (fp16)
__global__ __launch_bounds__(256) void k_dense2(
    const float* __restrict__ agg2, const __half* __restrict__ t2ph,
    const float* __restrict__ dinv,
    const float* __restrict__ b2, const float* __restrict__ W3,
    __half* __restrict__ t3ph) {
    __shared__ float sb2[32], sW3[512];
    int tid = threadIdx.x;
    if (tid < 32) sb2[tid] = b2[tid];
    for (int i = tid; i < 512; i += 256) sW3[i] = W3[i];
    __syncthreads();

    int n = blockIdx.x * 256 + tid;
    if (n >= N_NODES) return;
    float di = dinv[n];
    const float2* ag = reinterpret_cast<const float2*>(agg2 + (size_t)n * 32);
    const __half2* sp = reinterpret_cast<const __half2*>(t2ph + (size_t)n * 32);
    float h[32];
#pragma unroll
    for (int q = 0; q < 16; ++q) {
        float2 a = ag[q];
        float2 sv = __half22float2(sp[q]);
        h[2*q]   = fmaxf((a.x + sv.x) * di + sb2[2*q],   0.0f);
        h[2*q+1] = fmaxf((a.y + sv.y) * di + sb2[2*q+1], 0.0f);
    }
    float t[16];
#pragma unroll
    for (int k = 0; k < 16; ++k) t[k] = 0.0f;
    for (int j = 0; j < 32; ++j) {
#pragma unroll
        for (int k = 0; k < 16; ++k) t[k] += h[j] * sW3[j * 16 + k];
    }
    __half2* o = reinterpret_cast<__half2*>(t3ph + (size_t)n * 16);
#pragma unroll
    for (int q = 0; q < 8; ++q)
        o[q] = __floats2half2_rn(t[2*q] * di, t[2*q+1] * di);
}

// L3 gather + fused L3 finish + head dot: 4 lanes/node x 8B per edge.
__global__ __launch_bounds__(256) void k_g3(
    const __half* __restrict__ t3ph, const unsigned* __restrict__ pay,
    const int* __restrict__ row, const int* __restrict__ dgar,
    const float* __restrict__ dinv, const float* __restrict__ b3,
    const float* __restrict__ Wl, float* __restrict__ sval) {
    int tid = threadIdx.x;
    int lane = tid & 3;
    int n = blockIdx.x * 64 + (tid >> 2);
    if (n >= N_NODES) return;
    int r = row[n], d = dgar[n];
    const unsigned* P = pay + r;
    float a0 = 0, a1 = 0, a2 = 0, a3 = 0;
#pragma unroll 4
    for (int j = 0; j < d; ++j) {
        int sn = P[j] & 0x1FFFF;
        union { uint2 u; __half2 h[2]; } U;
        U.u = *reinterpret_cast<const uint2*>(t3ph + (size_t)sn * 16 + lane * 4);
        float2 f0 = __half22float2(U.h[0]);
        float2 f1 = __half22float2(U.h[1]);
        a0 += f0.x; a1 += f0.y; a2 += f1.x; a3 += f1.y;
    }
    union { uint2 u; __half2 h[2]; } S;
    S.u = *reinterpret_cast<const uint2*>(t3ph + (size_t)n * 16 + lane * 4);
    float2 s0 = __half22float2(S.h[0]);
    float2 s1 = __half22float2(S.h[1]);
    float di = dinv[n];
    float p = ((a0 + s0.x) * di + b3[lane * 4 + 0]) * Wl[lane * 4 + 0]
            + ((a1 + s0.y) * di + b3[lane * 4 + 1]) * Wl[lane * 4 + 1]
            + ((a2 + s1.x) * di + b3[lane * 4 + 2]) * Wl[lane * 4 + 2]
            + ((a3 + s1.y) * di + b3[lane * 4 + 3]) * Wl[lane * 4 + 3];
    p += __shfl_xor(p, 1);
    p += __shfl_xor(p, 2);
    if (lane == 0) sval[n] = p;
}

// mean-pool + head per graph: binary-search + wave reduce. No atomics.
__global__ __launch_bounds__(64) void k_poolg(
    const float* __restrict__ sval, const int* __restrict__ batch,
    const float* __restrict__ bl, float* __restrict__ out) {
    int g = blockIdx.x;
    int lo = 0, hi = N_NODES;
    while (lo < hi) { int m = (lo + hi) >> 1; if (batch[m] < g) lo = m + 1; else hi = m; }
    int s0 = lo;
    hi = N_NODES;
    while (lo < hi) { int m = (lo + hi) >> 1; if (batch[m] < g + 1) lo = m + 1; else hi = m; }
    int s1 = lo;
    float s = 0.0f;
    for (int i = s0 + threadIdx.x; i < s1; i += 64) s += sval[i];
#pragma unroll
    for (int o = 32; o > 0; o >>= 1) s += __shfl_down(s, o);
    if (threadIdx.x == 0) {
        float c = fmaxf((float)(s1 - s0), 1.0f);
        out[g] = fmaxf(s / c + bl[0], 0.0f);
    }
}

extern "C" void kernel_launch(void* const* d_in, const int* in_sizes, int n_in,
                              void* d_out, int out_size, void* d_ws, size_t ws_size,
                              hipStream_t stream) {
    const float* x  = (const float*)d_in[0];
    const float* W1 = (const float*)d_in[1];
    const float* b1 = (const float*)d_in[2];
    const float* W2 = (const float*)d_in[3];
    const float* b2 = (const float*)d_in[4];
    const float* W3 = (const float*)d_in[5];
    const float* b3 = (const float*)d_in[6];
    const float* Wl = (const float*)d_in[7];
    const float* bl = (const float*)d_in[8];
    const int*   ei = (const int*)d_in[9];        // [2, E] row-major
    const int* batch = (const int*)d_in[10];
    const int* src = ei;
    const int* dst = ei + N_EDGES;
    float* out = (float*)d_out;

    const size_t N = N_NODES;
    char* ws = (char*)d_ws;
    float*    dinv = (float*)   (ws);
    float*    xp   = (float*)   (ws + 4 * (N));
    __half*   t2ph = (__half*)  (ws + 4 * (5 * N));
    __half*   t3ph = (__half*)  (ws + 4 * (21 * N));
    float*    agg1 = (float*)   (ws + 4 * (29 * N));
    float*    agg2 = (float*)   (ws + 4 * (33 * N));
    float*    sval = (float*)   (ws + 4 * (65 * N));
    int*      row  = (int*)     (ws + 4 * (81 * N));
    int*      dgar = (int*)     (ws + 4 * (82 * N));
    int*      bcnt = (int*)     (ws + 4 * (83 * N));
    unsigned* pay  = (unsigned*)(ws + 4 * (83 * N + NB));

    const int B = 256;
    const int gN = (N_NODES + B - 1) / B;            // 391
    const int gB = (N_EDGES + EPB - 1) / EPB;        // 391
    const int gG = (N_NODES + 63) / 64;              // 1563

    k_zero  <<<(NB + B - 1) / B, B, 0, stream>>>(bcnt);
    k_bucket<<<gB, B, 0, stream>>>(src, dst, bcnt, pay);
    k_sort  <<<NB, B, 0, stream>>>(pay, bcnt, x, dinv, xp, row, dgar);
    k_g1    <<<gG, B, 0, stream>>>(xp, pay, row, dgar, agg1);
    k_dense1<<<gN, B, 0, stream>>>(agg1, xp, dinv, W1, b1, W2, t2ph);
    k_g2    <<<gG, B, 0, stream>>>(t2ph, pay, row, dgar, agg2);
    k_dense2<<<gN, B, 0, stream>>>(agg2, t2ph, dinv, b2, W3, t3ph);
    k_g3    <<<gG, B, 0, stream>>>(t3ph, pay, row, dgar, dinv, b3, Wl, sval);
    k_poolg <<<N_GRAPHS, 64, 0, stream>>>(sval, batch, bl, out);
}

// Round 18
// 250.256 us; speedup vs baseline: 1.1358x; 1.0106x over previous
//
#include <hip/hip_runtime.h>
#include <hip/hip_fp16.h>

#define N_NODES 100000
#define N_EDGES 3200000
#define N_GRAPHS 1000
#define NB 1024            // dst-range buckets
#define NPB 98             // nodes per bucket
#define CAP 3584           // per-bucket edge capacity (mean 3136 + 8 sigma)
#define EPB 8192           // edges per bucketing block
#define BT 512             // bucketing threads per block
#define EPT 16             // edges per thread (EPB/BT)
#define NCH 8              // src chunks (t2ph slice 0.8MB fits L2)
#define CHN 12500          // nodes per chunk
#define PBINS (NPB * NCH)  // 784 composite sort bins

// ---------------- workspace layout (element offsets, 4B units) --------------
// dinv : float[N]        @ 0
// xp   : float[4N]       @ N
// t2ph : half [32N]      @ 5N    (16N units)
// t3ph : half [16N]      @ 21N   (8N units)
// agg1 : float[4N]       @ 29N
// agg2 : float[32N]      @ 33N
// sval : float[N]        @ 65N
// row  : int  [N]        @ 81N
// dgar : int  [N]        @ 82N
// bcnt : int  [NB]       @ 83N
// pay  : uint [NB*CAP]   @ 83N+NB   packed (src | local_dst<<17), (ld,chunk)-sorted
// total ≈ 12.0M units ≈ 48 MB

__global__ void k_zero(int* __restrict__ bcnt) {
    int i = blockIdx.x * blockDim.x + threadIdx.x;
    if (i < NB) bcnt[i] = 0;
}

// two-level bucketize by dst; records decoded once into registers. 42KB LDS,
// 512 threads (8 waves) per block for latency hiding.
__global__ __launch_bounds__(BT) void k_bucket(
    const int* __restrict__ src, const int* __restrict__ dst,
    int* __restrict__ bcnt, unsigned* __restrict__ pay) {
    __shared__ int cnt[NB];
    __shared__ int off[NB];
    __shared__ int scanbuf[BT];
    __shared__ unsigned rec[EPB];   // 32KB

    int tid = threadIdx.x;
    int e0 = blockIdx.x * EPB;
    for (int i = tid; i < NB; i += BT) cnt[i] = 0;
    __syncthreads();

    unsigned wreg[EPT], breg[EPT];
#pragma unroll
    for (int k = 0; k < EPT; ++k) {
        int e = e0 + k * BT + tid;
        if (e < N_EDGES) {
            unsigned s = (unsigned)src[e];
            unsigned d = (unsigned)dst[e];
            unsigned b = d / NPB;
            unsigned ld = d - b * NPB;
            wreg[k] = s | (ld << 17);
            breg[k] = b;
            atomicAdd(&cnt[b], 1);
        } else {
            breg[k] = 0xFFFFFFFFu;
        }
    }
    __syncthreads();

    // exclusive scan of cnt[1024]: thread owns 2 consecutive buckets
    int base = tid * 2;
    int c0 = cnt[base], c1 = cnt[base + 1];
    int part = c0 + c1;
    scanbuf[tid] = part;
    __syncthreads();
    for (int o = 1; o < BT; o <<= 1) {
        int v = (tid >= o) ? scanbuf[tid - o] : 0;
        __syncthreads();
        scanbuf[tid] += v;
        __syncthreads();
    }
    int ex = scanbuf[tid] - part;
    off[base]     = ex;
    off[base + 1] = ex + c0;
    __syncthreads();

#pragma unroll
    for (int k = 0; k < EPT; ++k) {
        if (breg[k] != 0xFFFFFFFFu) {
            int p = atomicAdd(&off[breg[k]], 1);
            rec[p] = wreg[k];
        }
    }
    __syncthreads();

    for (int b = tid; b < NB; b += BT) {
        int c = cnt[b];
        if (c == 0) continue;
        int ls = off[b] - c;
        int gb = atomicAdd(&bcnt[b], c);
        unsigned* dstp = pay + (size_t)b * CAP;
        for (int k = 0; k < c; ++k) {
            int gp = gb + k;
            if (gp < CAP) dstp[gp] = rec[ls + k];
        }
    }
}

// per-bucket: counting-sort by composite key (local_dst*8 + src_chunk) -> CSR
// whose per-node segments are src-chunk-ordered (L2-phased gathers).
// Also emits row/dgar and fused prep (dinv + pre-scaled xp).
__global__ __launch_bounds__(256) void k_sort(
    unsigned* __restrict__ pay, const int* __restrict__ bcnt,
    const float* __restrict__ x, float* __restrict__ dinv,
    float* __restrict__ xp, int* __restrict__ row, int* __restrict__ dgar) {
    __shared__ unsigned rec[CAP], rec2[CAP];            // 28.7KB
    __shared__ int cnb[PBINS], exl[PBINS], ofl[PBINS];  // 9.4KB
    __shared__ int scanbuf[256];
    int tid = threadIdx.x;
    int b = blockIdx.x;
    int cnt = bcnt[b]; if (cnt > CAP) cnt = CAP;
    unsigned* P = pay + (size_t)b * CAP;

    for (int i = tid; i < PBINS; i += 256) cnb[i] = 0;
    __syncthreads();

    for (int i = tid; i < cnt; i += 256) {
        unsigned w = P[i];
        rec[i] = w;
        int key = (int)(w >> 17) * NCH + (int)((w & 0x1FFFF) / CHN);
        atomicAdd(&cnb[key], 1);
    }
    __syncthreads();

    // exclusive scan of cnb[784]: thread t<196 owns bins 4t..4t+3
    int part = 0, c0 = 0, c1 = 0, c2 = 0, c3 = 0;
    int base = tid * 4;
    if (base < PBINS) {
        c0 = cnb[base]; c1 = cnb[base + 1]; c2 = cnb[base + 2]; c3 = cnb[base + 3];
        part = c0 + c1 + c2 + c3;
    }
    scanbuf[tid] = part;
    __syncthreads();
    for (int o = 1; o < 256; o <<= 1) {
        int v = (tid >= o) ? scanbuf[tid - o] : 0;
        __syncthreads();
        scanbuf[tid] += v;
        __syncthreads();
    }
    if (base < PBINS) {
        int ex = scanbuf[tid] - part;
        exl[base]     = ex;
        exl[base + 1] = ex + c0;
        exl[base + 2] = ex + c0 + c1;
        exl[base + 3] = ex + c0 + c1 + c2;
        ofl[base]     = exl[base];
        ofl[base + 1] = exl[base + 1];
        ofl[base + 2] = exl[base + 2];
        ofl[base + 3] = exl[base + 3];
    }
    __syncthreads();

    // CSR metadata + fused prep for this bucket's own nodes
    if (tid < NPB) {
        int n = b * NPB + tid;
        if (n < N_NODES) {
            int s0 = exl[tid * NCH];
            int s1 = exl[tid * NCH + NCH - 1] + cnb[tid * NCH + NCH - 1];
            row[n]  = b * CAP + s0;
            int dg  = s1 - s0;
            dgar[n] = dg;
            float di = rsqrtf((float)(dg + 1));   // +1 self-loop
            dinv[n] = di;
            float4 v = reinterpret_cast<const float4*>(x)[n];
            v.x *= di; v.y *= di; v.z *= di; v.w *= di;
            reinterpret_cast<float4*>(xp)[n] = v;
        }
    }
    __syncthreads();

    for (int i = tid; i < cnt; i += 256) {
        unsigned w = rec[i];
        int key = (int)(w >> 17) * NCH + (int)((w & 0x1FFFF) / CHN);
        int p = atomicAdd(&ofl[key], 1);
        rec2[p] = w;
    }
    __syncthreads();

    for (int i = tid; i < cnt; i += 256) P[i] = rec2[i];
}

// L1 gather: 4 lanes/node, register accumulate (xp = 1.6MB, L2-resident)
__global__ __launch_bounds__(256) void k_g1(
    const float* __restrict__ xp, const unsigned* __restrict__ pay,
    const int* __restrict__ row, const int* __restrict__ dgar,
    float* __restrict__ agg1) {
    int tid = threadIdx.x;
    int lane = tid & 3;
    int n = blockIdx.x * 64 + (tid >> 2);
    if (n >= N_NODES) return;
    int r = row[n], d = dgar[n];
    const unsigned* P = pay + r;
    float acc = 0.0f;
#pragma unroll 4
    for (int j = 0; j < d; ++j) {
        int sn = P[j] & 0x1FFFF;
        acc += xp[sn * 4 + lane];
    }
    agg1[(size_t)n * 4 + lane] = acc;
}

// finish L1: a=(agg1+self)*dinv -> relu(@W1+b1) -> @W2 -> *dinv -> t2ph (fp16)
__global__ __launch_bounds__(256) void k_dense1(
    const float* __restrict__ agg1, const float* __restrict__ xp,
    const float* __restrict__ dinv,
    const float* __restrict__ W1, const float* __restrict__ b1,
    const float* __restrict__ W2, __half* __restrict__ t2ph) {
    __shared__ float sW1[256], sb1[64], sW2[2048];
    int tid = threadIdx.x;
    sW1[tid] = W1[tid];
    if (tid < 64) sb1[tid] = b1[tid];
    for (int i = tid; i < 2048; i += 256) sW2[i] = W2[i];
    __syncthreads();

    int n = blockIdx.x * 256 + tid;
    if (n >= N_NODES) return;
    float di = dinv[n];
    float4 ag = reinterpret_cast<const float4*>(agg1)[n];
    float4 sv = reinterpret_cast<const float4*>(xp)[n];
    float a[4] = {(ag.x + sv.x) * di, (ag.y + sv.y) * di,
                  (ag.z + sv.z) * di, (ag.w + sv.w) * di};
    float t[32];
#pragma unroll
    for (int k = 0; k < 32; ++k) t[k] = 0.0f;
    for (int j = 0; j < 64; ++j) {
        float h = sb1[j];
#pragma unroll
        for (int i = 0; i < 4; ++i) h += a[i] * sW1[i * 64 + j];
        h = fmaxf(h, 0.0f);
#pragma unroll
        for (int k = 0; k < 32; ++k) t[k] += h * sW2[j * 32 + k];
    }
    __half2* o = reinterpret_cast<__half2*>(t2ph + (size_t)n * 32);
#pragma unroll
    for (int q = 0; q < 16; ++q)
        o[q] = __floats2half2_rn(t[2*q] * di, t[2*q+1] * di);
}

// L2 gather: 4 lanes/node x 16B per edge; edge lists are src-chunk-ordered
__global__ __launch_bounds__(256) void k_g2(
    const __half* __restrict__ t2ph, const unsigned* __restrict__ pay,
    const int* __restrict__ row, const int* __restrict__ dgar,
    float* __restrict__ agg2) {
    int tid = threadIdx.x;
    int lane = tid & 3;
    int n = blockIdx.x * 64 + (tid >> 2);
    if (n >= N_NODES) return;
    int r = row[n], d = dgar[n];
    const unsigned* P = pay + r;
    float a0 = 0, a1 = 0, a2 = 0, a3 = 0, a4 = 0, a5 = 0, a6 = 0, a7 = 0;
#pragma unroll 4
    for (int j = 0; j < d; ++j) {
        int sn = P[j] & 0x1FFFF;
        union { uint4 u; __half2 h[4]; } U;
        U.u = *reinterpret_cast<const uint4*>(t2ph + (size_t)sn * 32 + lane * 8);
        float2 f0 = __half22float2(U.h[0]);
        float2 f1 = __half22float2(U.h[1]);
        float2 f2 = __half22float2(U.h[2]);
        float2 f3 = __half22float2(U.h[3]);
        a0 += f0.x; a1 += f0.y; a2 += f1.x; a3 += f1.y;
        a4 += f2.x; a5 += f2.y; a6 += f3.x; a7 += f3.y;
    }
    float4* o = reinterpret_cast<float4*>(agg2 + (size_t)n * 32 + lane * 8);
    o[0] = make_float4(a0, a1, a2, a3);
    o[1] = make_float4(a4, a5, a6, a7);
}

// finish L2: h=relu((agg2+self)*dinv+b2) -> @W3 -> *dinv -> t3ph (fp16)
__global__ __launch_bounds__(256) void k_dense2(
    const float* __restrict__ agg2, const __half* __restrict__ t2ph,
    const float* __restrict__ dinv,
    const float* __restrict__ b2, const float* __restrict__ W3,
    __half* __restrict__ t3ph) {
    __shared__ float sb2[32], sW3[512];
    int tid = threadIdx.x;
    if (tid < 32) sb2[tid] = b2[tid];
    for (int i = tid; i < 512; i += 256) sW3[i] = W3[i];
    __syncthreads();

    int n = blockIdx.x * 256 + tid;
    if (n >= N_NODES) return;
    float di = dinv[n];
    const float2* ag = reinterpret_cast<const float2*>(agg2 + (size_t)n * 32);
    const __half2* sp = reinterpret_cast<const __half2*>(t2ph + (size_t)n * 32);
    float h[32];
#pragma unroll
    for (int q = 0; q < 16; ++q) {
        float2 a = ag[q];
        float2 sv = __half22float2(sp[q]);
        h[2*q]   = fmaxf((a.x + sv.x) * di + sb2[2*q],   0.0f);
        h[2*q+1] = fmaxf((a.y + sv.y) * di + sb2[2*q+1], 0.0f);
    }
    float t[16];
#pragma unroll
    for (int k = 0; k < 16; ++k) t[k] = 0.0f;
    for (int j = 0; j < 32; ++j) {
#pragma unroll
        for (int k = 0; k < 16; ++k) t[k] += h[j] * sW3[j * 16 + k];
    }
    __half2* o = reinterpret_cast<__half2*>(t3ph + (size_t)n * 16);
#pragma unroll
    for (int q = 0; q < 8; ++q)
        o[q] = __floats2half2_rn(t[2*q] * di, t[2*q+1] * di);
}

// L3 gather + fused L3 finish + head dot: 4 lanes/node x 8B per edge.
__global__ __launch_bounds__(256) void k_g3(
    const __half* __restrict__ t3ph, const unsigned* __restrict__ pay,
    const int* __restrict__ row, const int* __restrict__ dgar,
    const float* __restrict__ dinv, const float* __restrict__ b3,
    const float* __restrict__ Wl, float* __restrict__ sval) {
    int tid = threadIdx.x;
    int lane = tid & 3;
    int n = blockIdx.x * 64 + (tid >> 2);
    if (n >= N_NODES) return;
    int r = row[n], d = dgar[n];
    const unsigned* P = pay + r;
    float a0 = 0, a1 = 0, a2 = 0, a3 = 0;
#pragma unroll 4
    for (int j = 0; j < d; ++j) {
        int sn = P[j] & 0x1FFFF;
        union { uint2 u; __half2 h[2]; } U;
        U.u = *reinterpret_cast<const uint2*>(t3ph + (size_t)sn * 16 + lane * 4);
        float2 f0 = __half22float2(U.h[0]);
        float2 f1 = __half22float2(U.h[1]);
        a0 += f0.x; a1 += f0.y; a2 += f1.x; a3 += f1.y;
    }
    union { uint2 u; __half2 h[2]; } S;
    S.u = *reinterpret_cast<const uint2*>(t3ph + (size_t)n * 16 + lane * 4);
    float2 s0 = __half22float2(S.h[0]);
    float2 s1 = __half22float2(S.h[1]);
    float di = dinv[n];
    float p = ((a0 + s0.x) * di + b3[lane * 4 + 0]) * Wl[lane * 4 + 0]
            + ((a1 + s0.y) * di + b3[lane * 4 + 1]) * Wl[lane * 4 + 1]
            + ((a2 + s1.x) * di + b3[lane * 4 + 2]) * Wl[lane * 4 + 2]
            + ((a3 + s1.y) * di + b3[lane * 4 + 3]) * Wl[lane * 4 + 3];
    p += __shfl_xor(p, 1);
    p += __shfl_xor(p, 2);
    if (lane == 0) sval[n] = p;
}

// mean-pool + head per graph: binary-search + wave reduce. No atomics.
__global__ __launch_bounds__(64) void k_poolg(
    const float* __restrict__ sval, const int* __restrict__ batch,
    const float* __restrict__ bl, float* __restrict__ out) {
    int g = blockIdx.x;
    int lo = 0, hi = N_NODES;
    while (lo < hi) { int m = (lo + hi) >> 1; if (batch[m] < g) lo = m + 1; else hi = m; }
    int s0 = lo;
    hi = N_NODES;
    while (lo < hi) { int m = (lo + hi) >> 1; if (batch[m] < g + 1) lo = m + 1; else hi = m; }
    int s1 = lo;
    float s = 0.0f;
    for (int i = s0 + threadIdx.x; i < s1; i += 64) s += sval[i];
#pragma unroll
    for (int o = 32; o > 0; o >>= 1) s += __shfl_down(s, o);
    if (threadIdx.x == 0) {
        float c = fmaxf((float)(s1 - s0), 1.0f);
        out[g] = fmaxf(s / c + bl[0], 0.0f);
    }
}

extern "C" void kernel_launch(void* const* d_in, const int* in_sizes, int n_in,
                              void* d_out, int out_size, void* d_ws, size_t ws_size,
                              hipStream_t stream) {
    const float* x  = (const float*)d_in[0];
    const float* W1 = (const float*)d_in[1];
    const float* b1 = (const float*)d_in[2];
    const float* W2 = (const float*)d_in[3];
    const float* b2 = (const float*)d_in[4];
    const float* W3 = (const float*)d_in[5];
    const float* b3 = (const float*)d_in[6];
    const float* Wl = (const float*)d_in[7];
    const float* bl = (const float*)d_in[8];
    const int*   ei = (const int*)d_in[9];        // [2, E] row-major
    const int* batch = (const int*)d_in[10];
    const int* src = ei;
    const int* dst = ei + N_EDGES;
    float* out = (float*)d_out;

    const size_t N = N_NODES;
    char* ws = (char*)d_ws;
    float*    dinv = (float*)   (ws);
    float*    xp   = (float*)   (ws + 4 * (N));
    __half*   t2ph = (__half*)  (ws + 4 * (5 * N));
    __half*   t3ph = (__half*)  (ws + 4 * (21 * N));
    float*    agg1 = (float*)   (ws + 4 * (29 * N));
    float*    agg2 = (float*)   (ws + 4 * (33 * N));
    float*    sval = (float*)   (ws + 4 * (65 * N));
    int*      row  = (int*)     (ws + 4 * (81 * N));
    int*      dgar = (int*)     (ws + 4 * (82 * N));
    int*      bcnt = (int*)     (ws + 4 * (83 * N));
    unsigned* pay  = (unsigned*)(ws + 4 * (83 * N + NB));

    const int B = 256;
    const int gN = (N_NODES + B - 1) / B;            // 391
    const int gB = (N_EDGES + EPB - 1) / EPB;        // 391
    const int gG = (N_NODES + 63) / 64;              // 1563

    k_zero  <<<(NB + B - 1) / B, B, 0, stream>>>(bcnt);
    k_bucket<<<gB, BT, 0, stream>>>(src, dst, bcnt, pay);
    k_sort  <<<NB, B, 0, stream>>>(pay, bcnt, x, dinv, xp, row, dgar);
    k_g1    <<<gG, B, 0, stream>>>(xp, pay, row, dgar, agg1);
    k_dense1<<<gN, B, 0, stream>>>(agg1, xp, dinv, W1, b1, W2, t2ph);
    k_g2    <<<gG, B, 0, stream>>>(t2ph, pay, row, dgar, agg2);
    k_dense2<<<gN, B, 0, stream>>>(agg2, t2ph, dinv, b2, W3, t3ph);
    k_g3    <<<gG, B, 0, stream>>>(t3ph, pay, row, dgar, dinv, b3, Wl, sval);
    k_poolg <<<N_GRAPHS, 64, 0, stream>>>(sval, batch, bl, out);
}